// Round 4
// baseline (46.893 us; speedup 1.0000x reference)
//
#include <hip/hip_runtime.h>

#define B_ 2048
#define V_ 2048
#define C_ 512
#define M_ 8
#define H_ 16
#define NB 2            // rows per compute block
#define CHUNK 256       // columns per compute block == blockDim.x
#define NCOMPUTE ((C_ / CHUNK) * (B_ / NB))   // 2048 compute blocks
#define NCOPY (B_ / 2)                        // 1024 copy blocks, 2 rows each

typedef float f32x2 __attribute__((ext_vector_type(2)));

__device__ __forceinline__ float fast_exp2(float x) { return __builtin_amdgcn_exp2f(x); }
__device__ __forceinline__ float fast_rcp(float x)  { return __builtin_amdgcn_rcpf(x); }

#define LOG2E 1.4426950408889634f

// Zero-trans packed reciprocal: int-magic seed (~5% rel err) + 2 Newton -> ~6e-6.
// Valid for positive normal d (here d in [945, ~1.2e7]).
__device__ __forceinline__ f32x2 fast_pk_rcp(f32x2 d) {
    f32x2 r;
    r.x = __uint_as_float(0x7EF311C3u - __float_as_uint(d.x));
    r.y = __uint_as_float(0x7EF311C3u - __float_as_uint(d.y));
    const f32x2 two = {2.0f, 2.0f};
    r = r * __builtin_elementwise_fma(-d, r, two);   // pk_fma(neg) + pk_mul
    r = r * __builtin_elementwise_fma(-d, r, two);
    return r;
}

// Packed Pade[5/4] tanh: x*(945+105y+y^2)/(945+420y+15y^2), y=x^2.
// Max err ~1.3e-3 near |x|~3.6; tail (|x|>3.8) handled by med3 clamp to [-1,1].
__device__ __forceinline__ f32x2 pk_tanh(f32x2 x,
                                         const f32x2 c105, const f32x2 c945,
                                         const f32x2 c15,  const f32x2 c420) {
    f32x2 y  = x * x;                                   // pk_mul
    f32x2 n  = y + c105;                                // pk_add
    n        = __builtin_elementwise_fma(y, n, c945);   // pk_fma
    f32x2 dd = __builtin_elementwise_fma(y, c15, c420); // pk_fma
    dd       = __builtin_elementwise_fma(y, dd, c945);  // pk_fma
    f32x2 xn = x * n;                                   // pk_mul
    f32x2 r  = fast_pk_rcp(dd);                         // 6 full-rate issues
    f32x2 t  = xn * r;                                  // pk_mul
    t.x = __builtin_amdgcn_fmed3f(t.x, -1.0f, 1.0f);    // v_med3_f32
    t.y = __builtin_amdgcn_fmed3f(t.y, -1.0f, 1.0f);
    return t;
}

__global__ __launch_bounds__(256) void grad_attn_kernel(
    const float* __restrict__ preds,
    const int*   __restrict__ mask_ids,
    const float* __restrict__ W1,
    const float* __restrict__ b1,
    const float* __restrict__ W2,
    float*       __restrict__ out)
{
    const int tid = threadIdx.x;
    const int bi  = blockIdx.x;

    if (bi >= NCOMPUTE) {
        // ---- pure copy region: cols [C_, V_) of 2 rows ----
        const int r0 = (bi - NCOMPUTE) * 2;
        #pragma unroll
        for (int r = 0; r < 2; ++r) {
            const float4* src = reinterpret_cast<const float4*>(preds + (size_t)(r0 + r) * V_ + C_);
            float4*       dst = reinterpret_cast<float4*>(out + (size_t)(r0 + r) * V_ + C_);
            #pragma unroll
            for (int j = tid; j < (V_ - C_) / 4; j += 256) dst[j] = src[j];
        }
        return;
    }

    const int chunk  = bi & 1;
    const int rowgrp = bi >> 1;
    const int b0 = rowgrp * NB;
    const int c  = chunk * CHUNK + tid;

    // ---- weights in registers (unscaled now; b2 cancels in softmax) ----
    float w1a[H_], w1b[H_], bb[H_], w2[H_];
    {
        const float4* W1v = reinterpret_cast<const float4*>(W1 + (size_t)c * 2 * H_);
        const float4* b1v = reinterpret_cast<const float4*>(b1 + (size_t)c * H_);
        const float4* W2v = reinterpret_cast<const float4*>(W2 + (size_t)c * H_);
        #pragma unroll
        for (int i = 0; i < H_ / 4; ++i) {
            *reinterpret_cast<float4*>(&w1a[4 * i]) = W1v[i];
            *reinterpret_cast<float4*>(&w1b[4 * i]) = W1v[H_ / 4 + i];
            *reinterpret_cast<float4*>(&bb[4 * i])  = b1v[i];
            *reinterpret_cast<float4*>(&w2[4 * i])  = W2v[i];
        }
    }

    int midx[M_];
    {
        const int4* mi = reinterpret_cast<const int4*>(mask_ids + (size_t)c * M_);
        int4 a = mi[0], b = mi[1];
        midx[0] = a.x; midx[1] = a.y; midx[2] = a.z; midx[3] = a.w;
        midx[4] = b.x; midx[5] = b.y; midx[6] = b.z; midx[7] = b.w;
    }

    const f32x2 c105 = {105.0f, 105.0f};
    const f32x2 c945 = {945.0f, 945.0f};
    const f32x2 c15  = {15.0f, 15.0f};
    const f32x2 c420 = {420.0f, 420.0f};

    #pragma unroll
    for (int r = 0; r < NB; ++r) {
        const float* row = preds + (size_t)(b0 + r) * V_;
        float ha = row[c];
        f32x2 hm2[M_ / 2];
        #pragma unroll
        for (int p = 0; p < M_ / 2; ++p) {
            hm2[p].x = row[midx[2 * p]];
            hm2[p].y = row[midx[2 * p + 1]];
        }

        f32x2 sc[M_ / 2];
        #pragma unroll
        for (int p = 0; p < M_ / 2; ++p) sc[p] = (f32x2){0.0f, 0.0f};

        #pragma unroll
        for (int h = 0; h < H_; ++h) {
            float pa = fmaf(ha, w1a[h], bb[h]);
            f32x2 pav = {pa, pa};
            f32x2 wbv = {w1b[h], w1b[h]};
            f32x2 w2v = {w2[h], w2[h]};
            #pragma unroll
            for (int p = 0; p < M_ / 2; ++p) {
                f32x2 x = __builtin_elementwise_fma(hm2[p], wbv, pav);  // pk_fma
                f32x2 t = pk_tanh(x, c105, c945, c15, c420);            // 14 issues, 0 trans
                sc[p] = __builtin_elementwise_fma(t, w2v, sc[p]);       // pk_fma
            }
        }

        // softmax over M (no max-subtract: |score| <= sum|w2| ~ 6, exp2 safe)
        const f32x2 l2ev = {LOG2E, LOG2E};
        f32x2 ex[M_ / 2];
        #pragma unroll
        for (int p = 0; p < M_ / 2; ++p) {
            f32x2 sl = sc[p] * l2ev;
            ex[p].x = fast_exp2(sl.x);
            ex[p].y = fast_exp2(sl.y);
        }
        f32x2 s2 = (ex[0] + ex[1]) + (ex[2] + ex[3]);
        f32x2 w2s = __builtin_elementwise_fma(ex[0], hm2[0],
                    __builtin_elementwise_fma(ex[1], hm2[1],
                    __builtin_elementwise_fma(ex[2], hm2[2],
                    ex[3] * hm2[3])));
        float sum = s2.x + s2.y;
        float ws  = w2s.x + w2s.y;
        float corrected = fmaxf(ha, fmaf(ws, fast_rcp(sum), 1e-6f));
        out[(size_t)(b0 + r) * V_ + c] = corrected;
    }
}

extern "C" void kernel_launch(void* const* d_in, const int* in_sizes, int n_in,
                              void* d_out, int out_size, void* d_ws, size_t ws_size,
                              hipStream_t stream) {
    const float* preds    = (const float*)d_in[0];
    const int*   mask_ids = (const int*)d_in[2];
    const float* W1       = (const float*)d_in[3];
    const float* b1       = (const float*)d_in[4];
    const float* W2       = (const float*)d_in[5];
    float* out = (float*)d_out;

    dim3 grid(NCOMPUTE + NCOPY);
    dim3 block(256);
    grad_attn_kernel<<<grid, block, 0, stream>>>(preds, mask_ids, W1, b1, W2, out);
}